// Round 1
// baseline (100.158 us; speedup 1.0000x reference)
//
#include <hip/hip_runtime.h>

// Problem constants from setup_inputs(): x[8,256,64,64] f32, kernel[8,1,9,64,64] f32, K=3, dilation=1.
constexpr int Nn = 8, Cc = 256, Hh = 64, Ww = 64;
constexpr int CHUNK = 64;   // channels per block -> grid = N*H*(C/CHUNK) = 2048 blocks

__global__ __launch_bounds__(256) void ddf_kernel(const float* __restrict__ x,
                                                  const float* __restrict__ ker,
                                                  float* __restrict__ out) {
    const int b  = blockIdx.x;
    const int cb = b & 3;          // channel quarter
    const int h  = (b >> 2) & 63;  // row (uniform per block)
    const int n  = b >> 8;         // batch

    const int t  = threadIdx.x;
    const int wg = t & 15;         // w-group: 16 groups x 4 floats = full row of 64
    const int cl = t >> 4;         // channel lane 0..15
    const int w0 = wg << 2;

    // Hoist the 9 filter values for this (n,h,w0..w0+3). Shared across all channels.
    float4 kf[9];
    const float* kbase = ker + ((size_t)(n * 9) * Hh + h) * Ww + w0;
#pragma unroll
    for (int tap = 0; tap < 9; ++tap)
        kf[tap] = *reinterpret_cast<const float4*>(kbase + (size_t)tap * Hh * Ww);

#pragma unroll
    for (int it = 0; it < CHUNK / 16; ++it) {
        const int c = cb * CHUNK + it * 16 + cl;
        const float* xc = x + ((size_t)(n * Cc + c) * Hh) * Ww;

        float4 acc = {0.f, 0.f, 0.f, 0.f};
#pragma unroll
        for (int r = 0; r < 3; ++r) {
            const int hh = h + r - 1;          // block-uniform branch
            if (hh < 0 || hh >= Hh) continue;  // zero padding row
            const float* row = xc + (size_t)hh * Ww;

            const float4 v = *reinterpret_cast<const float4*>(row + w0);
            const float lm = (w0 > 0)       ? row[w0 - 1] : 0.f;  // left halo
            const float rp = (w0 + 4 < Ww)  ? row[w0 + 4] : 0.f;  // right halo

            const float4 k0 = kf[r * 3 + 0];  // kw = 0 -> x[w-1]
            const float4 k1 = kf[r * 3 + 1];  // kw = 1 -> x[w]
            const float4 k2 = kf[r * 3 + 2];  // kw = 2 -> x[w+1]

            acc.x += k0.x * lm  + k1.x * v.x + k2.x * v.y;
            acc.y += k0.y * v.x + k1.y * v.y + k2.y * v.z;
            acc.z += k0.z * v.y + k1.z * v.z + k2.z * v.w;
            acc.w += k0.w * v.z + k1.w * v.w + k2.w * rp;
        }
        *reinterpret_cast<float4*>(out + ((size_t)(n * Cc + c) * Hh + h) * Ww + w0) = acc;
    }
}

extern "C" void kernel_launch(void* const* d_in, const int* in_sizes, int n_in,
                              void* d_out, int out_size, void* d_ws, size_t ws_size,
                              hipStream_t stream) {
    const float* x   = (const float*)d_in[0];
    const float* ker = (const float*)d_in[1];
    // d_in[2] = kernel_size(=3), d_in[3] = dilation(=1): fixed by setup_inputs, hardcoded.
    float* out = (float*)d_out;

    const int grid = Nn * Hh * (Cc / CHUNK);  // 2048
    ddf_kernel<<<grid, 256, 0, stream>>>(x, ker, out);
}

// Round 2
// 96.270 us; speedup vs baseline: 1.0404x; 1.0404x over previous
//
#include <hip/hip_runtime.h>

// x[8,256,64,64] f32, kernel[8,1,9,64,64] f32, K=3, dilation=1.
// out[n,c,h,w] = sum_{r,s} x[n,c,h+r-1,w+s-1] * ker[n,0,r*3+s,h,w]
constexpr int Cc = 256, Hh = 64, Ww = 64;
constexpr int NCH  = 4;  // channels per thread
constexpr int HSEG = 4;  // rows per block -> x rows loaded (HSEG+2)/HSEG = 1.5x

struct Row { float4 v; float lm, rp; };

// Load one 4-wide x row segment + halos. `valid` is block-uniform (row in range).
// Halos come from the lane+-1 neighbor (w-strip is the fast lane index); strips
// 0 and 15 get the zero padding directly.
__device__ __forceinline__ Row load_row(const float* __restrict__ rowptr, bool valid,
                                        int w0, int wstrip, int lane) {
    Row r;
    if (valid) r.v = *reinterpret_cast<const float4*>(rowptr + w0);
    else       r.v = make_float4(0.f, 0.f, 0.f, 0.f);
    const float l  = __shfl(r.v.w, (lane + 63) & 63);
    const float rr = __shfl(r.v.x, (lane + 1) & 63);
    r.lm = (wstrip == 0)  ? 0.f : l;
    r.rp = (wstrip == 15) ? 0.f : rr;
    return r;
}

__device__ __forceinline__ void conv_row(float4& acc, const Row& r,
                                         const float4& k0, const float4& k1, const float4& k2) {
    acc.x += k0.x * r.lm  + k1.x * r.v.x + k2.x * r.v.y;
    acc.y += k0.y * r.v.x + k1.y * r.v.y + k2.y * r.v.z;
    acc.z += k0.z * r.v.y + k1.z * r.v.z + k2.z * r.v.w;
    acc.w += k0.w * r.v.z + k1.w * r.v.w + k2.w * r.rp;
}

__global__ __launch_bounds__(256) void ddf_kernel(const float* __restrict__ x,
                                                  const float* __restrict__ ker,
                                                  float* __restrict__ out) {
    const int b  = blockIdx.x;
    const int hs = b & (Hh / HSEG - 1);   // h segment (16)
    const int cb = (b >> 4) & 3;          // channel quarter
    const int n  = b >> 6;                // batch
    const int h0 = hs * HSEG;

    const int t      = threadIdx.x;
    const int lane   = t & 63;
    const int wstrip = t & 15;            // fast index -> lane+-1 are w neighbors
    const int w0     = wstrip << 2;
    const int chl    = t >> 4;            // channel lane 0..15

    const float* kcol = ker + ((size_t)n * 9 * Hh) * Ww + w0;

    const float* xc[NCH];
    float*       oc[NCH];
#pragma unroll
    for (int i = 0; i < NCH; ++i) {
        const int c = cb * 64 + i * 16 + chl;
        xc[i] = x   + ((size_t)(n * Cc + c) * Hh) * Ww;
        oc[i] = out + ((size_t)(n * Cc + c) * Hh) * Ww;
    }

    // Prime the rolling window: rows h0-1, h0.
    Row r0[NCH], r1[NCH];
#pragma unroll
    for (int i = 0; i < NCH; ++i) {
        r0[i] = load_row(xc[i] + (size_t)(h0 - 1) * Ww, h0 > 0, w0, wstrip, lane);
        r1[i] = load_row(xc[i] + (size_t)h0 * Ww,       true,   w0, wstrip, lane);
    }

#pragma unroll
    for (int dh = 0; dh < HSEG; ++dh) {
        const int h = h0 + dh;

        // 9 filter values for this (n,h,w0..w0+3); shared by all 16 channel lanes.
        float4 kf[9];
#pragma unroll
        for (int tap = 0; tap < 9; ++tap)
            kf[tap] = *reinterpret_cast<const float4*>(kcol + ((size_t)tap * Hh + h) * Ww);

        const bool vnext = (h + 1) < Hh;   // block-uniform
        Row r2[NCH];
#pragma unroll
        for (int i = 0; i < NCH; ++i)
            r2[i] = load_row(xc[i] + (size_t)(h + 1) * Ww, vnext, w0, wstrip, lane);

#pragma unroll
        for (int i = 0; i < NCH; ++i) {
            float4 acc = make_float4(0.f, 0.f, 0.f, 0.f);
            conv_row(acc, r0[i], kf[0], kf[1], kf[2]);
            conv_row(acc, r1[i], kf[3], kf[4], kf[5]);
            conv_row(acc, r2[i], kf[6], kf[7], kf[8]);
            *reinterpret_cast<float4*>(oc[i] + (size_t)h * Ww + w0) = acc;
            r0[i] = r1[i];   // register rotation (free under full unroll)
            r1[i] = r2[i];
        }
    }
}

extern "C" void kernel_launch(void* const* d_in, const int* in_sizes, int n_in,
                              void* d_out, int out_size, void* d_ws, size_t ws_size,
                              hipStream_t stream) {
    const float* x   = (const float*)d_in[0];
    const float* ker = (const float*)d_in[1];
    float* out = (float*)d_out;

    const int grid = 8 * (Cc / 64) * (Hh / HSEG);  // 8n * 4cb * 16hs = 512 blocks
    ddf_kernel<<<grid, 256, 0, stream>>>(x, ker, out);
}

// Round 3
// 90.313 us; speedup vs baseline: 1.1090x; 1.0660x over previous
//
#include <hip/hip_runtime.h>

// x[8,256,64,64] f32, kernel[8,1,9,64,64] f32, K=3, dilation=1.
// out[n,c,h,w] = sum_{r,s} x[n,c,h+r-1,w+s-1] * ker[n,0,r*3+s,h,w]
constexpr int Cc = 256, Hh = 64, Ww = 64;
constexpr int NCH   = 2;   // channels per thread
constexpr int CHUNK = 32;  // channels per block
constexpr int HSEG  = 4;   // rows per block -> x rows loaded 1.5x, grid = 1024

struct Row { float4 v; float lm, rp; };

__device__ __forceinline__ Row load_row(const float* __restrict__ rowptr, bool valid,
                                        int w0, int wstrip, int lane) {
    Row r;
    if (valid) r.v = *reinterpret_cast<const float4*>(rowptr + w0);
    else       r.v = make_float4(0.f, 0.f, 0.f, 0.f);
    const float l  = __shfl(r.v.w, (lane + 63) & 63);
    const float rr = __shfl(r.v.x, (lane + 1) & 63);
    r.lm = (wstrip == 0)  ? 0.f : l;   // w-strip is the fast lane index
    r.rp = (wstrip == 15) ? 0.f : rr;
    return r;
}

__device__ __forceinline__ void conv_row(float4& acc, const Row& r,
                                         const float4& k0, const float4& k1, const float4& k2) {
    acc.x += k0.x * r.lm  + k1.x * r.v.x + k2.x * r.v.y;
    acc.y += k0.y * r.v.x + k1.y * r.v.y + k2.y * r.v.z;
    acc.z += k0.z * r.v.y + k1.z * r.v.z + k2.z * r.v.w;
    acc.w += k0.w * r.v.z + k1.w * r.v.w + k2.w * r.rp;
}

__global__ __launch_bounds__(256) void ddf_kernel(const float* __restrict__ x,
                                                  const float* __restrict__ ker,
                                                  float* __restrict__ out) {
    const int b  = blockIdx.x;
    const int hs = b & 15;          // 16 h-segments
    const int cb = (b >> 4) & 7;    // 8 channel chunks of 32
    const int n  = b >> 7;          // batch
    const int h0 = hs * HSEG;

    const int t      = threadIdx.x;
    const int lane   = t & 63;
    const int wstrip = t & 15;
    const int w0     = wstrip << 2;
    const int chl    = t >> 4;      // 0..15

    // ---- Stage the block's kernel taps into LDS: 9 taps x 4 rows x 64 w = 9 KB.
    // Per tap the 4 rows are 256 contiguous floats (h,w contiguous in ker).
    __shared__ float4 klds[9 * 64];   // klds[tap*64 + dh*16 + wq]
    const float4* kerf4 = reinterpret_cast<const float4*>(ker) + (size_t)n * 9 * 1024;
    for (int j = t; j < 9 * 64; j += 256) {
        const int tap = j >> 6, q = j & 63;
        klds[j] = kerf4[(size_t)tap * 1024 + h0 * 16 + q];
    }

    const float* xc[NCH];
    float*       oc[NCH];
#pragma unroll
    for (int i = 0; i < NCH; ++i) {
        const int c = cb * CHUNK + i * 16 + chl;
        xc[i] = x   + ((size_t)(n * Cc + c) * Hh) * Ww;
        oc[i] = out + ((size_t)(n * Cc + c) * Hh) * Ww;
    }

    // Prime rolling window (rows h0-1, h0) while the LDS stage is in flight.
    Row r0[NCH], r1[NCH];
#pragma unroll
    for (int i = 0; i < NCH; ++i) {
        r0[i] = load_row(xc[i] + (size_t)(h0 - 1) * Ww, h0 > 0, w0, wstrip, lane);
        r1[i] = load_row(xc[i] + (size_t)h0 * Ww,       true,   w0, wstrip, lane);
    }
    __syncthreads();

#pragma unroll
    for (int dh = 0; dh < HSEG; ++dh) {
        const int h = h0 + dh;

        float4 kf[9];
#pragma unroll
        for (int tap = 0; tap < 9; ++tap)
            kf[tap] = klds[tap * 64 + dh * 16 + wstrip];   // 16 lanes broadcast x4

        const bool vnext = (h + 1) < Hh;   // block-uniform
        Row r2[NCH];
#pragma unroll
        for (int i = 0; i < NCH; ++i)
            r2[i] = load_row(xc[i] + (size_t)(h + 1) * Ww, vnext, w0, wstrip, lane);

#pragma unroll
        for (int i = 0; i < NCH; ++i) {
            float4 acc = make_float4(0.f, 0.f, 0.f, 0.f);
            conv_row(acc, r0[i], kf[0], kf[1], kf[2]);
            conv_row(acc, r1[i], kf[3], kf[4], kf[5]);
            conv_row(acc, r2[i], kf[6], kf[7], kf[8]);
            *reinterpret_cast<float4*>(oc[i] + (size_t)h * Ww + w0) = acc;
            r0[i] = r1[i];
            r1[i] = r2[i];
        }
    }
}

extern "C" void kernel_launch(void* const* d_in, const int* in_sizes, int n_in,
                              void* d_out, int out_size, void* d_ws, size_t ws_size,
                              hipStream_t stream) {
    const float* x   = (const float*)d_in[0];
    const float* ker = (const float*)d_in[1];
    float* out = (float*)d_out;

    const int grid = 8 * (Cc / CHUNK) * (Hh / HSEG);  // 8 * 8 * 16 = 1024
    ddf_kernel<<<grid, 256, 0, stream>>>(x, ker, out);
}